// Round 2
// baseline (431.134 us; speedup 1.0000x reference)
//
#include <hip/hip_runtime.h>

// B = 64 == wavefront size; lane = batch index throughout.
// Pipeline: prep (transpose x -> xT[N,64], zero cnt)
//           hist (cnt[dst[e]]++), scan (exclusive prefix -> off, cursor)
//           scatter (counting-sort edges into dst-contiguous CSR)
//           reduce (per-node register accumulation, zero atomics,
//                   fused epilogue with LDS transpose for coalesced out)

__global__ void prep_kernel(const float* __restrict__ x, float* __restrict__ xT,
                            int* __restrict__ cnt, int N) {
    __shared__ float tile[64][65];  // +1 pad: conflict-free transposed reads
    int n0 = blockIdx.x * 64;
    int tid = threadIdx.x;
    for (int lin = tid; lin < 64 * 64; lin += 256) {
        int nl = lin & 63, b = lin >> 6;
        int n = n0 + nl;
        tile[b][nl] = (n < N) ? x[(long)b * N + n] : 0.f;
    }
    __syncthreads();
    for (int lin = tid; lin < 64 * 64; lin += 256) {
        int b = lin & 63, nl = lin >> 6;
        int n = n0 + nl;
        if (n < N) xT[(long)n * 64 + b] = tile[b][nl];
    }
    if (tid < 64) {
        int n = n0 + tid;
        if (n < N) cnt[n] = 0;
    }
}

__global__ void hist_kernel(const int* __restrict__ dst, int* __restrict__ cnt, int E) {
    int e = blockIdx.x * blockDim.x + threadIdx.x;
    if (e < E) atomicAdd(&cnt[dst[e]], 1);
}

__global__ __launch_bounds__(1024) void scan_kernel(const int* __restrict__ cnt,
                                                    int* __restrict__ off,
                                                    int* __restrict__ cursor, int N) {
    __shared__ int p0[1024];
    __shared__ int p1[1024];
    int t = threadIdx.x;
    int per = (N + 1023) / 1024;
    int lo = t * per, hi = min(N, lo + per);
    int s = 0;
    for (int i = lo; i < hi; ++i) s += cnt[i];
    p0[t] = s;
    __syncthreads();
    int* a = p0; int* b = p1;
    for (int d = 1; d < 1024; d <<= 1) {
        int v = a[t] + ((t >= d) ? a[t - d] : 0);
        b[t] = v;
        __syncthreads();
        int* tmp = a; a = b; b = tmp;
    }
    int run = a[t] - s;  // exclusive base for this thread's chunk
    for (int i = lo; i < hi; ++i) {
        off[i] = run;
        cursor[i] = run;
        run += cnt[i];
    }
    if (t == 1023) off[N] = a[1023];
}

__global__ void scatter_kernel(const float* __restrict__ adj, const float* __restrict__ w,
                               const int* __restrict__ src, const int* __restrict__ dst,
                               int* __restrict__ cursor, int* __restrict__ sorted_src,
                               float* __restrict__ sorted_coef, int E) {
    int e = blockIdx.x * blockDim.x + threadIdx.x;
    if (e < E) {
        int d = dst[e];
        int p = atomicAdd(&cursor[d], 1);
        sorted_src[p] = src[e];
        sorted_coef[p] = adj[e] * w[e];
    }
}

__global__ __launch_bounds__(512) void reduce_kernel(
        const int* __restrict__ off, const int* __restrict__ sorted_src,
        const float* __restrict__ sorted_coef, const float* __restrict__ xT,
        const float* __restrict__ x, const float* __restrict__ self_w,
        const float* __restrict__ bias, float* __restrict__ out, int N) {
    __shared__ float tile[64][65];  // [n_local][b], pad -> (lane+b)%32 banks on read
    int n0 = blockIdx.x * 64;
    int wave = threadIdx.x >> 6;    // 0..7
    int lane = threadIdx.x & 63;    // batch index
    for (int i = 0; i < 8; ++i) {
        int nl = wave * 8 + i;
        int n = n0 + nl;
        float acc = 0.f;
        if (n < N) {
            int s = __builtin_amdgcn_readfirstlane(off[n]);
            int t = __builtin_amdgcn_readfirstlane(off[n + 1]);
            for (int j = s; j < t; ++j) {
                int sj = sorted_src[j];       // wave-uniform -> scalar load
                float c = sorted_coef[j];     // wave-uniform -> scalar load
                acc += c * xT[sj * 64 + lane];  // coalesced 256B gather
            }
        }
        tile[nl][lane] = acc;
    }
    __syncthreads();
    int n = n0 + lane;
    float sl = 0.f, bi = 0.f;
    if (n < N) { sl = x[n] * self_w[n]; bi = bias[n]; }  // self-loop uses x row 0 (ref quirk)
    for (int i = 0; i < 8; ++i) {
        int b = wave * 8 + i;
        if (n < N) {
            float v = tile[lane][b] * sl + bi;
            out[(long)b * N + n] = fmaxf(v, 0.f);   // coalesced over n
        }
    }
}

extern "C" void kernel_launch(void* const* d_in, const int* in_sizes, int n_in,
                              void* d_out, int out_size, void* d_ws, size_t ws_size,
                              hipStream_t stream) {
    const float* x      = (const float*)d_in[0];
    const float* adj    = (const float*)d_in[1];
    const float* w      = (const float*)d_in[2];
    const float* self_w = (const float*)d_in[3];
    const float* bias   = (const float*)d_in[4];
    const int*   src    = (const int*)d_in[5];
    const int*   dst    = (const int*)d_in[6];

    int N = in_sizes[3];            // 20000
    int E = in_sizes[1];            // 1,280,000
    (void)n_in; (void)ws_size; (void)out_size;

    // workspace layout (all 4-byte elements)
    float* xT          = (float*)d_ws;                    // N*64
    int*   cnt         = (int*)(xT + (size_t)N * 64);     // N
    int*   off         = cnt + N;                         // N+1
    int*   cursor      = off + (N + 1);                   // N
    int*   sorted_src  = cursor + N;                      // E
    float* sorted_coef = (float*)(sorted_src + E);        // E
    float* out         = (float*)d_out;

    int nb64 = (N + 63) / 64;       // 313
    int nbE  = (E + 255) / 256;     // 5000

    hipLaunchKernelGGL(prep_kernel, dim3(nb64), dim3(256), 0, stream, x, xT, cnt, N);
    hipLaunchKernelGGL(hist_kernel, dim3(nbE), dim3(256), 0, stream, dst, cnt, E);
    hipLaunchKernelGGL(scan_kernel, dim3(1), dim3(1024), 0, stream, cnt, off, cursor, N);
    hipLaunchKernelGGL(scatter_kernel, dim3(nbE), dim3(256), 0, stream,
                       adj, w, src, dst, cursor, sorted_src, sorted_coef, E);
    hipLaunchKernelGGL(reduce_kernel, dim3(nb64), dim3(512), 0, stream,
                       off, sorted_src, sorted_coef, xT, x, self_w, bias, out, N);
}

// Round 3
// 256.228 us; speedup vs baseline: 1.6826x; 1.6826x over previous
//
#include <hip/hip_runtime.h>

// B = 64 == wavefront size; lane = batch index throughout.
// Pipeline: prep (x -> xT[N,64] transpose, zero cnt)
//           hist (cnt[dst[e]]++, int4 loads)
//           3-stage parallel exclusive scan -> off[N+1], cursor[N]
//           scatter (counting sort; one packed 8B (coef,src) store per edge)
//           reduce (one wave per node, 8-deep gather ILP, zero atomics)

typedef unsigned long long u64;

__global__ void prep_kernel(const float* __restrict__ x, float* __restrict__ xT,
                            int* __restrict__ cnt, int N) {
    __shared__ float tile[64][65];
    int n0 = blockIdx.x * 64;
    int tid = threadIdx.x;
    for (int lin = tid; lin < 64 * 64; lin += 256) {
        int nl = lin & 63, b = lin >> 6;
        int n = n0 + nl;
        tile[b][nl] = (n < N) ? x[(long)b * N + n] : 0.f;
    }
    __syncthreads();
    for (int lin = tid; lin < 64 * 64; lin += 256) {
        int b = lin & 63, nl = lin >> 6;
        int n = n0 + nl;
        if (n < N) xT[(long)n * 64 + b] = tile[b][nl];
    }
    if (tid < 64) {
        int n = n0 + tid;
        if (n < N) cnt[n] = 0;
    }
}

__global__ void hist_kernel(const int* __restrict__ dst, int* __restrict__ cnt, int E4) {
    int i = blockIdx.x * blockDim.x + threadIdx.x;
    if (i < E4) {
        int4 d = ((const int4*)dst)[i];
        atomicAdd(&cnt[d.x], 1);
        atomicAdd(&cnt[d.y], 1);
        atomicAdd(&cnt[d.z], 1);
        atomicAdd(&cnt[d.w], 1);
    }
}

// --- 3-stage scan: cnt[N] -> off[N+1] (exclusive), cursor = copy of off[0..N)
__global__ void scan_a(const int* __restrict__ cnt, int* __restrict__ chunk_sum, int N) {
    __shared__ int sm[256];
    int i = blockIdx.x * 256 + threadIdx.x;
    sm[threadIdx.x] = (i < N) ? cnt[i] : 0;
    __syncthreads();
    for (int d = 128; d > 0; d >>= 1) {
        if (threadIdx.x < d) sm[threadIdx.x] += sm[threadIdx.x + d];
        __syncthreads();
    }
    if (threadIdx.x == 0) chunk_sum[blockIdx.x] = sm[0];
}

__global__ void scan_b(const int* __restrict__ chunk_sum, int* __restrict__ chunk_base, int NC) {
    // NC <= 128; single block of 128, simple LDS scan
    __shared__ int sm[128];
    int t = threadIdx.x;
    sm[t] = (t < NC) ? chunk_sum[t] : 0;
    __syncthreads();
    for (int d = 1; d < 128; d <<= 1) {
        int v = sm[t];
        if (t >= d) v += sm[t - d];
        __syncthreads();
        sm[t] = v;
        __syncthreads();
    }
    if (t < NC) chunk_base[t] = sm[t] - chunk_sum[t];  // exclusive
}

__global__ void scan_c(const int* __restrict__ cnt, const int* __restrict__ chunk_base,
                       int* __restrict__ off, int* __restrict__ cursor, int N) {
    __shared__ int sm[256];
    int t = threadIdx.x;
    int i = blockIdx.x * 256 + t;
    int c = (i < N) ? cnt[i] : 0;
    sm[t] = c;
    __syncthreads();
    for (int d = 1; d < 256; d <<= 1) {
        int v = sm[t];
        if (t >= d) v += sm[t - d];
        __syncthreads();
        sm[t] = v;
        __syncthreads();
    }
    int incl = sm[t];
    if (i < N) {
        int ex = chunk_base[blockIdx.x] + incl - c;
        off[i] = ex;
        cursor[i] = ex;
        if (i == N - 1) off[N] = chunk_base[blockIdx.x] + incl;
    }
}

__global__ void scatter_kernel(const float* __restrict__ adj, const float* __restrict__ w,
                               const int* __restrict__ src, const int* __restrict__ dst,
                               int* __restrict__ cursor, u64* __restrict__ packed, int E) {
    int e = blockIdx.x * blockDim.x + threadIdx.x;
    if (e < E) {
        int d = dst[e];
        float c = adj[e] * w[e];
        int p = atomicAdd(&cursor[d], 1);
        packed[p] = ((u64)__float_as_uint(c) << 32) | (unsigned int)src[e];
    }
}

__global__ __launch_bounds__(512) void reduce_kernel(
        const int* __restrict__ off, const u64* __restrict__ packed,
        const float* __restrict__ xT, const float* __restrict__ x,
        const float* __restrict__ self_w, const float* __restrict__ bias,
        float* __restrict__ out, int N) {
    int wave = threadIdx.x >> 6;            // 0..7
    int lane = threadIdx.x & 63;            // batch index
    int n = blockIdx.x * 8 + wave;          // one wave per node
    if (n >= N) return;
    int s = __builtin_amdgcn_readfirstlane(off[n]);
    int t = __builtin_amdgcn_readfirstlane(off[n + 1]);
    float acc = 0.f;
    int j = s;
    // 8-deep ILP: 8 independent gathers in flight per chunk
    for (; j + 8 <= t; j += 8) {
        u64 p[8];
#pragma unroll
        for (int k = 0; k < 8; ++k) p[k] = packed[j + k];
        float g[8];
#pragma unroll
        for (int k = 0; k < 8; ++k) {
            int sk = (int)(unsigned int)p[k];
            float ck = __uint_as_float((unsigned int)(p[k] >> 32));
            g[k] = ck * xT[sk * 64 + lane];
        }
        acc += ((g[0] + g[1]) + (g[2] + g[3])) + ((g[4] + g[5]) + (g[6] + g[7]));
    }
    for (; j < t; ++j) {
        u64 pk = packed[j];
        int sk = (int)(unsigned int)pk;
        float ck = __uint_as_float((unsigned int)(pk >> 32));
        acc += ck * xT[sk * 64 + lane];
    }
    float sl = x[n] * self_w[n];            // self-loop uses x row 0 (ref quirk)
    float v = acc * sl + bias[n];
    out[(long)lane * N + n] = fmaxf(v, 0.f);  // 4B scattered stores; L2 merges
}

extern "C" void kernel_launch(void* const* d_in, const int* in_sizes, int n_in,
                              void* d_out, int out_size, void* d_ws, size_t ws_size,
                              hipStream_t stream) {
    const float* x      = (const float*)d_in[0];
    const float* adj    = (const float*)d_in[1];
    const float* w      = (const float*)d_in[2];
    const float* self_w = (const float*)d_in[3];
    const float* bias   = (const float*)d_in[4];
    const int*   src    = (const int*)d_in[5];
    const int*   dst    = (const int*)d_in[6];

    int N = in_sizes[3];            // 20000
    int E = in_sizes[1];            // 1,280,000
    (void)n_in; (void)ws_size; (void)out_size;

    // workspace layout: packed first (8B-aligned at base), then 4B arrays
    u64*   packed     = (u64*)d_ws;                       // E
    float* xT         = (float*)(packed + E);             // N*64
    int*   cnt        = (int*)(xT + (size_t)N * 64);      // N
    int*   off        = cnt + N;                          // N+1
    int*   cursor     = off + (N + 1);                    // N
    int*   chunk_sum  = cursor + N;                       // <=128
    int*   chunk_base = chunk_sum + 128;                  // <=128
    float* out        = (float*)d_out;

    int nb64 = (N + 63) / 64;       // 313
    int NC   = (N + 255) / 256;     // 79
    int E4   = E / 4;               // E divisible by 4 here

    hipLaunchKernelGGL(prep_kernel, dim3(nb64), dim3(256), 0, stream, x, xT, cnt, N);
    hipLaunchKernelGGL(hist_kernel, dim3((E4 + 255) / 256), dim3(256), 0, stream, dst, cnt, E4);
    hipLaunchKernelGGL(scan_a, dim3(NC), dim3(256), 0, stream, cnt, chunk_sum, N);
    hipLaunchKernelGGL(scan_b, dim3(1), dim3(128), 0, stream, chunk_sum, chunk_base, NC);
    hipLaunchKernelGGL(scan_c, dim3(NC), dim3(256), 0, stream, cnt, chunk_base, off, cursor, N);
    hipLaunchKernelGGL(scatter_kernel, dim3((E + 255) / 256), dim3(256), 0, stream,
                       adj, w, src, dst, cursor, packed, E);
    hipLaunchKernelGGL(reduce_kernel, dim3((N + 7) / 8), dim3(512), 0, stream,
                       off, packed, xT, x, self_w, bias, out, N);
}